// Round 5
// baseline (930.173 us; speedup 1.0000x reference)
//
#include <hip/hip_runtime.h>
#include <stdint.h>

// ---------------------------------------------------------------------------
// torch-ngp hashgrid encode (16 levels, dim 2) + 32->64->8 ReLU MLP, 8-corner
// trilinear blend.  One thread per (point, outer corner); 8 threads/point are
// consecutive lanes -> shuffle reduction + coalesced store.
//
// R5 changes vs R4 (362us, Occ 43%, LDS 32KB, VALUBusy 36%, MfmaUtil 4.4%):
//  * H LDS round-trip deleted: layer-1 C/D col (=lane&15) equals layer-2
//    B-frag n-index, and the needed k rows are exactly this lane's hacc regs
//    -> bh[e] = bf16(relu(hacc[e>>2][nt][e&3])), pure register repack.
//  * F hi/lo planes staged SEQUENTIALLY through one 4KB/wave buffer
//    (write hi -> read frags -> overwrite lo -> read), intra-wave lgkmcnt
//    fences only.  LDS/block 32KB -> 16KB.
//  * __launch_bounds__(256,8): VGPR 64 (R4-demonstrated) * LDS 16KB ->
//    theoretical 8 blocks/CU (32 waves).  Tripwire: WRITE_SIZE ~8192KB,
//    else spills -> revert to (256,6).
//  MLP arithmetic bit-identical to passing R4 (absmax 0.00195).
// ---------------------------------------------------------------------------

#define BLK 256
#define R15 513

typedef short short8 __attribute__((ext_vector_type(8)));
typedef float f32x4 __attribute__((ext_vector_type(4)));

__device__ __forceinline__ short bf16_hi(float x) {
    return (short)(__float_as_uint(x) >> 16);           // truncation split
}
__device__ __forceinline__ float bf16_back(short h) {
    return __uint_as_float(((uint32_t)(uint16_t)h) << 16);  // exact
}

// Linear (tight-grid) level: compile-time R/H/O so % H becomes magic-multiply.
template <int R, int H, int O>
__device__ __forceinline__ void enc_linear(float xcx, float xcy, float xcz,
                                           const float2* __restrict__ tab,
                                           float& f0, float& f1) {
    const float Rf = (float)R;
    float px = __fadd_rn(__fmul_rn(xcx, Rf), 0.5f);
    float py = __fadd_rn(__fmul_rn(xcy, Rf), 0.5f);
    float pz = __fadd_rn(__fmul_rn(xcz, Rf), 0.5f);
    float fpx = floorf(px), fpy = floorf(py), fpz = floorf(pz);
    float frx = px - fpx, fry = py - fpy, frz = pz - fpz;
    int gx = (int)fpx, gy = (int)fpy, gz = (int)fpz;
    float wx[2] = {1.f - frx, frx};
    float wy[2] = {1.f - fry, fry};
    float wz[2] = {1.f - frz, frz};
    const int R1 = R + 1;
    int xt[2] = {gx, gx + 1};
    int yt[2] = {gy * R1, gy * R1 + R1};
    int zt[2] = {gz * R1 * R1, gz * R1 * R1 + R1 * R1};
    float a0 = 0.f, a1 = 0.f;
#pragma unroll
    for (int c = 0; c < 8; ++c) {
        const int ox = (c >> 2) & 1, oy = (c >> 1) & 1, oz = c & 1;
        int id  = xt[ox] + yt[oy] + zt[oz];
        int idx = (int)((uint32_t)id % (uint32_t)H);
        float w = wx[ox] * wy[oy] * wz[oz];
        float2 tv = tab[O + idx];
        a0 = fmaf(w, tv.x, a0);
        a1 = fmaf(w, tv.y, a1);
    }
    f0 = a0; f1 = a1;
}

// Hashed level (H = 2^19): compile-time R/O, hand-CSE'd hash terms.
template <int RI, int O>
__device__ __forceinline__ void enc_hash(float xcx, float xcy, float xcz,
                                         const float2* __restrict__ tab,
                                         float& f0, float& f1) {
    const float Rf = (float)RI;
    float px = __fadd_rn(__fmul_rn(xcx, Rf), 0.5f);
    float py = __fadd_rn(__fmul_rn(xcy, Rf), 0.5f);
    float pz = __fadd_rn(__fmul_rn(xcz, Rf), 0.5f);
    float fpx = floorf(px), fpy = floorf(py), fpz = floorf(pz);
    float frx = px - fpx, fry = py - fpy, frz = pz - fpz;
    uint32_t gx = (uint32_t)(int)fpx, gy = (uint32_t)(int)fpy, gz = (uint32_t)(int)fpz;
    float wx[2] = {1.f - frx, frx};
    float wy[2] = {1.f - fry, fry};
    float wz[2] = {1.f - frz, frz};
    uint32_t xt[2] = {gx, gx + 1u};
    uint32_t yt[2] = {gy * 2654435761u, gy * 2654435761u + 2654435761u};
    uint32_t zt[2] = {gz * 805459861u,  gz * 805459861u  + 805459861u};
    float a0 = 0.f, a1 = 0.f;
#pragma unroll
    for (int c = 0; c < 8; ++c) {
        const int ox = (c >> 2) & 1, oy = (c >> 1) & 1, oz = c & 1;
        uint32_t idx = (xt[ox] ^ yt[oy] ^ zt[oz]) & 524287u;
        float w = wx[ox] * wy[oy] * wz[oz];
        float2 tv = tab[O + (int)idx];
        a0 = fmaf(w, tv.x, a0);
        a1 = fmaf(w, tv.y, a1);
    }
    f0 = a0; f1 = a1;
}

__global__ __launch_bounds__(BLK, 8)
void grid_fused(const float* __restrict__ xyz, const float* __restrict__ bound,
                const float* __restrict__ table, const float* __restrict__ w1,
                const float* __restrict__ w2, float* __restrict__ out, int N) {
    // per-wave 4 KB scratch: F bf16 plane (hi, then lo), later O fp32 (2KB)
    __shared__ __align__(16) char smem_raw[4 * 4096];

    const int tid = threadIdx.x;
    const int t = blockIdx.x * BLK + tid;
    const int p = t >> 3;
    const int a = t & 7;
    if (p >= N) return;

    const int wid  = tid >> 6;
    const int lane = tid & 63;
    const int q    = lane >> 4;   // 16-lane group (k-group for MFMA frags)
    const int cc   = lane & 15;   // within-group index (M/N index)
    char* wb = smem_raw + wid * 4096;

    const float2* tab = (const float2*)table;

    const float b = bound[0];
    float X = xyz[3 * p + 0], Y = xyz[3 * p + 1], Z = xyz[3 * p + 2];
    float cx = ((X + b) / (2.0f * b)) * 512.0f;
    float cy = ((Y + b) / (2.0f * b)) * 512.0f;
    float cz = ((Z + b) / (2.0f * b)) * 512.0f;
    float c0x = fmaxf(fminf(floorf(cx), 511.f), 0.f);
    float c0y = fmaxf(fminf(floorf(cy), 511.f), 0.f);
    float c0z = fmaxf(fminf(floorf(cz), 511.f), 0.f);
    float uu = cx - c0x, vv = cy - c0y, wwf = cz - c0z;

    const int ax = (a >> 2) & 1, ay = (a >> 1) & 1, az = a & 1;
    float xcx = (c0x + (float)ax) * (1.0f / 512.0f);
    float xcy = (c0y + (float)ay) * (1.0f / 512.0f);
    float xcz = (c0z + (float)az) * (1.0f / 512.0f);

    // ---- all 16 levels -> 32 feature registers (bit-identical encode) ------
    float fr[32];
    enc_linear<16,   4920,      0>(xcx, xcy, xcz, tab, fr[ 0], fr[ 1]);
    enc_linear<21,  10648,   4920>(xcx, xcy, xcz, tab, fr[ 2], fr[ 3]);
    enc_linear<26,  19688,  15568>(xcx, xcy, xcz, tab, fr[ 4], fr[ 5]);
    enc_linear<33,  39304,  35256>(xcx, xcy, xcz, tab, fr[ 6], fr[ 7]);
    enc_linear<41,  74088,  74560>(xcx, xcy, xcz, tab, fr[ 8], fr[ 9]);
    enc_linear<51, 140608, 148648>(xcx, xcy, xcz, tab, fr[10], fr[11]);
    enc_linear<65, 287496, 289256>(xcx, xcy, xcz, tab, fr[12], fr[13]);
    enc_hash< 81,  576752>(xcx, xcy, xcz, tab, fr[14], fr[15]);
    enc_hash<102, 1101040>(xcx, xcy, xcz, tab, fr[16], fr[17]);
    enc_hash<129, 1625328>(xcx, xcy, xcz, tab, fr[18], fr[19]);
    enc_hash<162, 2149616>(xcx, xcy, xcz, tab, fr[20], fr[21]);
    enc_hash<204, 2673904>(xcx, xcy, xcz, tab, fr[22], fr[23]);
    enc_hash<257, 3198192>(xcx, xcy, xcz, tab, fr[24], fr[25]);
    enc_hash<324, 3722480>(xcx, xcy, xcz, tab, fr[26], fr[27]);
    enc_hash<408, 4246768>(xcx, xcy, xcz, tab, fr[28], fr[29]);
    enc_hash<R15, 4771056>(xcx, xcy, xcz, tab, fr[30], fr[31]);

    // ======================= MFMA MLP ======================================
    // Per wave: H^T = W1^T(64x32) @ F^T(32x64); O^T = W2^T(8x64) @ H^T(64x64).
    // k-map for all A/B packs: (q,e) -> k = 4q+e (e<4), 16+4q+(e-4) (e>=4).
    // C/D layout (m89-verified): col=lane&15, row=4*(lane>>4)+reg.

    // ---- stage F hi plane -> read frags -> overwrite lo plane -> read ------
    short8 fbh[4], fbl[4];
    {
        short8* F = (short8*)wb;   // [qq*64 + lane], 16B per entry = 4KB
#pragma unroll
        for (int qq = 0; qq < 4; ++qq) {
            short8 vh;
#pragma unroll
            for (int e = 0; e < 8; ++e) {
                const int f = (e < 4) ? (4 * qq + e) : (16 + 4 * qq + (e - 4));
                vh[e] = bf16_hi(fr[f]);
            }
            F[qq * 64 + lane] = vh;
        }
        asm volatile("s_waitcnt lgkmcnt(0)" ::: "memory");
#pragma unroll
        for (int nt = 0; nt < 4; ++nt)
            fbh[nt] = *(const short8*)(wb + (q * 1024 + (16 * nt + cc) * 16));
        asm volatile("s_waitcnt lgkmcnt(0)" ::: "memory");  // reads done before overwrite
#pragma unroll
        for (int qq = 0; qq < 4; ++qq) {
            short8 vl;
#pragma unroll
            for (int e = 0; e < 8; ++e) {
                const int f = (e < 4) ? (4 * qq + e) : (16 + 4 * qq + (e - 4));
                float x = fr[f];
                short h = bf16_hi(x);
                vl[e] = bf16_hi(x - bf16_back(h));
            }
            F[qq * 64 + lane] = vl;
        }
        asm volatile("s_waitcnt lgkmcnt(0)" ::: "memory");
#pragma unroll
        for (int nt = 0; nt < 4; ++nt)
            fbl[nt] = *(const short8*)(wb + (q * 1024 + (16 * nt + cc) * 16));
        asm volatile("s_waitcnt lgkmcnt(0)" ::: "memory");
    }

    const f32x4 zero4 = {0.f, 0.f, 0.f, 0.f};
    f32x4 oacc[4] = {zero4, zero4, zero4, zero4};

#pragma unroll
    for (int kk = 0; kk < 2; ++kk) {
        // ---- layer 1, m-tiles {2kk, 2kk+1} -> hidden rows 32kk..32kk+31 ----
        f32x4 hacc[2][4];
#pragma unroll
        for (int ms = 0; ms < 2; ++ms)
#pragma unroll
            for (int nt = 0; nt < 4; ++nt) hacc[ms][nt] = zero4;

#pragma unroll
        for (int ms = 0; ms < 2; ++ms) {
            const int m = 2 * kk + ms;
            // A-frag of W1^T tile m: lane holds row 16m+cc, k = map(q,e)
            float wv[8];
#pragma unroll
            for (int e = 0; e < 8; ++e) {
                const int f = (e < 4) ? (4 * q + e) : (16 + 4 * q + (e - 4));
                wv[e] = w1[f * 64 + 16 * m + cc];
            }
            short8 ah, al;
#pragma unroll
            for (int e = 0; e < 8; ++e) {
                short h = bf16_hi(wv[e]);
                ah[e] = h;
                al[e] = bf16_hi(wv[e] - bf16_back(h));
            }
#pragma unroll
            for (int nt = 0; nt < 4; ++nt) {
                hacc[ms][nt] = __builtin_amdgcn_mfma_f32_16x16x32_bf16(ah, fbh[nt], hacc[ms][nt], 0, 0, 0);
                hacc[ms][nt] = __builtin_amdgcn_mfma_f32_16x16x32_bf16(ah, fbl[nt], hacc[ms][nt], 0, 0, 0);
                hacc[ms][nt] = __builtin_amdgcn_mfma_f32_16x16x32_bf16(al, fbh[nt], hacc[ms][nt], 0, 0, 0);
            }
        }

        // ---- layer 2 A-frag: W2^T, rows = out-dim (valid < 8), k = hidden --
        float wv2[8];
#pragma unroll
        for (int e = 0; e < 8; ++e) {
            const int hi_ = 32 * kk + 16 * (e >> 2) + 4 * q + (e & 3);
            const int cL = cc < 8 ? cc : 7;      // clamp addr, zero below
            float v = w2[hi_ * 8 + cL];
            wv2[e] = (cc < 8) ? v : 0.f;
        }
        short8 a2h, a2l;
#pragma unroll
        for (int e = 0; e < 8; ++e) {
            short h = bf16_hi(wv2[e]);
            a2h[e] = h;
            a2l[e] = bf16_hi(wv2[e] - bf16_back(h));
        }

        // ---- layer 2 B-frag is LANE-LOCAL: C/D col(=cc) == B-frag n(=cc),
        //      k row 4q+e / 16+4q+(e-4) == this lane's hacc[ms=e>>2][nt][e&3].
        //      Pure register repack; no LDS.  Values identical to R4's
        //      store/reload (same relu + truncation splits).
#pragma unroll
        for (int nt = 0; nt < 4; ++nt) {
            short8 bh, bl;
#pragma unroll
            for (int e = 0; e < 8; ++e) {
                float x = fmaxf(hacc[e >> 2][nt][e & 3], 0.f);
                short h = bf16_hi(x);
                bh[e] = h;
                bl[e] = bf16_hi(x - bf16_back(h));
            }
            oacc[nt] = __builtin_amdgcn_mfma_f32_16x16x32_bf16(a2h, bh, oacc[nt], 0, 0, 0);
            oacc[nt] = __builtin_amdgcn_mfma_f32_16x16x32_bf16(a2h, bl, oacc[nt], 0, 0, 0);
            oacc[nt] = __builtin_amdgcn_mfma_f32_16x16x32_bf16(a2l, bh, oacc[nt], 0, 0, 0);
        }
    }

    // ---- O^T (rows=out-j valid<8, cols=wave thread) -> per-thread rows -----
    {
        float* Ob = (float*)wb;                 // [j][t] : j*64 + t (2KB)
        if (q < 2) {
#pragma unroll
            for (int nt = 0; nt < 4; ++nt)
#pragma unroll
                for (int j = 0; j < 4; ++j)
                    Ob[(4 * q + j) * 64 + 16 * nt + cc] = oacc[nt][j];
        }
        asm volatile("s_waitcnt lgkmcnt(0)" ::: "memory");

        float o[8];
#pragma unroll
        for (int j = 0; j < 8; ++j) o[j] = Ob[j * 64 + lane];

        // ---- outer trilinear weight + 8-lane reduction ---------------------
        float wt = (ax ? uu : 1.f - uu) * (ay ? vv : 1.f - vv) * (az ? wwf : 1.f - wwf);
#pragma unroll
        for (int j = 0; j < 8; ++j) {
            float v = o[j] * wt;
            v += __shfl_xor(v, 1);
            v += __shfl_xor(v, 2);
            v += __shfl_xor(v, 4);
            o[j] = v;
        }
        float r01 = (a & 1) ? o[1] : o[0];
        float r23 = (a & 1) ? o[3] : o[2];
        float r45 = (a & 1) ? o[5] : o[4];
        float r67 = (a & 1) ? o[7] : o[6];
        float r03 = (a & 2) ? r23 : r01;
        float r47 = (a & 2) ? r67 : r45;
        float r   = (a & 4) ? r47 : r03;
        out[t] = r;
    }
}

extern "C" void kernel_launch(void* const* d_in, const int* in_sizes, int n_in,
                              void* d_out, int out_size, void* d_ws, size_t ws_size,
                              hipStream_t stream) {
    const float* xyz   = (const float*)d_in[0];
    const float* bound = (const float*)d_in[1];
    const float* table = (const float*)d_in[2];
    const float* w1    = (const float*)d_in[3];
    const float* w2    = (const float*)d_in[4];
    float* out = (float*)d_out;

    const int N = in_sizes[0] / 3;          // 262144
    const int threads = N * 8;              // one thread per (point, corner)
    const int blocks = (threads + BLK - 1) / BLK;
    grid_fused<<<blocks, BLK, 0, stream>>>(xyz, bound, table, w1, w2, out, N);
}

// Round 6
// 673.994 us; speedup vs baseline: 1.3801x; 1.3801x over previous
//
#include <hip/hip_runtime.h>
#include <stdint.h>

// ---------------------------------------------------------------------------
// torch-ngp hashgrid encode (16 levels, dim 2) + 32->64->8 ReLU MLP, 8-corner
// trilinear blend.  One thread per (point, outer corner); 8 threads/point are
// consecutive lanes -> shuffle reduction + coalesced store.
//
// R6 change vs R5 (862us, SPILL DISASTER) / R4 (362us, LDS-capped 43% occ):
//  * keep R5's structure (MFMA MLP, no H round-trip, 16KB LDS/block)
//  * __launch_bounds__(256,6): VGPR cap 85.  (256,8) forced the allocator
//    under an infeasible 64/32-VGPR cap TWICE (R3, R5) -> massive scratch
//    spills (WRITE_SIZE 8MB -> 1.1GB).  R4 demonstrated the same live set
//    fits in 64 VGPRs under a loose cap, so 85 has margin.  6 blocks/CU
//    (75% theo occupancy) vs R4's LDS-capped 5 (62.5% -> measured 43%).
//  Tripwires: WRITE_SIZE must be ~8192KB; VGPR_Count must be >=~64.
//  MLP arithmetic bit-identical to passing R4/R5 (absmax 0.00195).
// ---------------------------------------------------------------------------

#define BLK 256
#define R15 513

typedef short short8 __attribute__((ext_vector_type(8)));
typedef float f32x4 __attribute__((ext_vector_type(4)));

__device__ __forceinline__ short bf16_hi(float x) {
    return (short)(__float_as_uint(x) >> 16);           // truncation split
}
__device__ __forceinline__ float bf16_back(short h) {
    return __uint_as_float(((uint32_t)(uint16_t)h) << 16);  // exact
}

// Linear (tight-grid) level: compile-time R/H/O so % H becomes magic-multiply.
template <int R, int H, int O>
__device__ __forceinline__ void enc_linear(float xcx, float xcy, float xcz,
                                           const float2* __restrict__ tab,
                                           float& f0, float& f1) {
    const float Rf = (float)R;
    float px = __fadd_rn(__fmul_rn(xcx, Rf), 0.5f);
    float py = __fadd_rn(__fmul_rn(xcy, Rf), 0.5f);
    float pz = __fadd_rn(__fmul_rn(xcz, Rf), 0.5f);
    float fpx = floorf(px), fpy = floorf(py), fpz = floorf(pz);
    float frx = px - fpx, fry = py - fpy, frz = pz - fpz;
    int gx = (int)fpx, gy = (int)fpy, gz = (int)fpz;
    float wx[2] = {1.f - frx, frx};
    float wy[2] = {1.f - fry, fry};
    float wz[2] = {1.f - frz, frz};
    const int R1 = R + 1;
    int xt[2] = {gx, gx + 1};
    int yt[2] = {gy * R1, gy * R1 + R1};
    int zt[2] = {gz * R1 * R1, gz * R1 * R1 + R1 * R1};
    float a0 = 0.f, a1 = 0.f;
#pragma unroll
    for (int c = 0; c < 8; ++c) {
        const int ox = (c >> 2) & 1, oy = (c >> 1) & 1, oz = c & 1;
        int id  = xt[ox] + yt[oy] + zt[oz];
        int idx = (int)((uint32_t)id % (uint32_t)H);
        float w = wx[ox] * wy[oy] * wz[oz];
        float2 tv = tab[O + idx];
        a0 = fmaf(w, tv.x, a0);
        a1 = fmaf(w, tv.y, a1);
    }
    f0 = a0; f1 = a1;
}

// Hashed level (H = 2^19): compile-time R/O, hand-CSE'd hash terms.
template <int RI, int O>
__device__ __forceinline__ void enc_hash(float xcx, float xcy, float xcz,
                                         const float2* __restrict__ tab,
                                         float& f0, float& f1) {
    const float Rf = (float)RI;
    float px = __fadd_rn(__fmul_rn(xcx, Rf), 0.5f);
    float py = __fadd_rn(__fmul_rn(xcy, Rf), 0.5f);
    float pz = __fadd_rn(__fmul_rn(xcz, Rf), 0.5f);
    float fpx = floorf(px), fpy = floorf(py), fpz = floorf(pz);
    float frx = px - fpx, fry = py - fpy, frz = pz - fpz;
    uint32_t gx = (uint32_t)(int)fpx, gy = (uint32_t)(int)fpy, gz = (uint32_t)(int)fpz;
    float wx[2] = {1.f - frx, frx};
    float wy[2] = {1.f - fry, fry};
    float wz[2] = {1.f - frz, frz};
    uint32_t xt[2] = {gx, gx + 1u};
    uint32_t yt[2] = {gy * 2654435761u, gy * 2654435761u + 2654435761u};
    uint32_t zt[2] = {gz * 805459861u,  gz * 805459861u  + 805459861u};
    float a0 = 0.f, a1 = 0.f;
#pragma unroll
    for (int c = 0; c < 8; ++c) {
        const int ox = (c >> 2) & 1, oy = (c >> 1) & 1, oz = c & 1;
        uint32_t idx = (xt[ox] ^ yt[oy] ^ zt[oz]) & 524287u;
        float w = wx[ox] * wy[oy] * wz[oz];
        float2 tv = tab[O + (int)idx];
        a0 = fmaf(w, tv.x, a0);
        a1 = fmaf(w, tv.y, a1);
    }
    f0 = a0; f1 = a1;
}

__global__ __launch_bounds__(BLK, 6)
void grid_fused(const float* __restrict__ xyz, const float* __restrict__ bound,
                const float* __restrict__ table, const float* __restrict__ w1,
                const float* __restrict__ w2, float* __restrict__ out, int N) {
    // per-wave 4 KB scratch: F bf16 plane (hi, then lo), later O fp32 (2KB)
    __shared__ __align__(16) char smem_raw[4 * 4096];

    const int tid = threadIdx.x;
    const int t = blockIdx.x * BLK + tid;
    const int p = t >> 3;
    const int a = t & 7;
    if (p >= N) return;

    const int wid  = tid >> 6;
    const int lane = tid & 63;
    const int q    = lane >> 4;   // 16-lane group (k-group for MFMA frags)
    const int cc   = lane & 15;   // within-group index (M/N index)
    char* wb = smem_raw + wid * 4096;

    const float2* tab = (const float2*)table;

    const float b = bound[0];
    float X = xyz[3 * p + 0], Y = xyz[3 * p + 1], Z = xyz[3 * p + 2];
    float cx = ((X + b) / (2.0f * b)) * 512.0f;
    float cy = ((Y + b) / (2.0f * b)) * 512.0f;
    float cz = ((Z + b) / (2.0f * b)) * 512.0f;
    float c0x = fmaxf(fminf(floorf(cx), 511.f), 0.f);
    float c0y = fmaxf(fminf(floorf(cy), 511.f), 0.f);
    float c0z = fmaxf(fminf(floorf(cz), 511.f), 0.f);
    float uu = cx - c0x, vv = cy - c0y, wwf = cz - c0z;

    const int ax = (a >> 2) & 1, ay = (a >> 1) & 1, az = a & 1;
    float xcx = (c0x + (float)ax) * (1.0f / 512.0f);
    float xcy = (c0y + (float)ay) * (1.0f / 512.0f);
    float xcz = (c0z + (float)az) * (1.0f / 512.0f);

    // ---- all 16 levels -> 32 feature registers (bit-identical encode) ------
    float fr[32];
    enc_linear<16,   4920,      0>(xcx, xcy, xcz, tab, fr[ 0], fr[ 1]);
    enc_linear<21,  10648,   4920>(xcx, xcy, xcz, tab, fr[ 2], fr[ 3]);
    enc_linear<26,  19688,  15568>(xcx, xcy, xcz, tab, fr[ 4], fr[ 5]);
    enc_linear<33,  39304,  35256>(xcx, xcy, xcz, tab, fr[ 6], fr[ 7]);
    enc_linear<41,  74088,  74560>(xcx, xcy, xcz, tab, fr[ 8], fr[ 9]);
    enc_linear<51, 140608, 148648>(xcx, xcy, xcz, tab, fr[10], fr[11]);
    enc_linear<65, 287496, 289256>(xcx, xcy, xcz, tab, fr[12], fr[13]);
    enc_hash< 81,  576752>(xcx, xcy, xcz, tab, fr[14], fr[15]);
    enc_hash<102, 1101040>(xcx, xcy, xcz, tab, fr[16], fr[17]);
    enc_hash<129, 1625328>(xcx, xcy, xcz, tab, fr[18], fr[19]);
    enc_hash<162, 2149616>(xcx, xcy, xcz, tab, fr[20], fr[21]);
    enc_hash<204, 2673904>(xcx, xcy, xcz, tab, fr[22], fr[23]);
    enc_hash<257, 3198192>(xcx, xcy, xcz, tab, fr[24], fr[25]);
    enc_hash<324, 3722480>(xcx, xcy, xcz, tab, fr[26], fr[27]);
    enc_hash<408, 4246768>(xcx, xcy, xcz, tab, fr[28], fr[29]);
    enc_hash<R15, 4771056>(xcx, xcy, xcz, tab, fr[30], fr[31]);

    // ======================= MFMA MLP ======================================
    // Per wave: H^T = W1^T(64x32) @ F^T(32x64); O^T = W2^T(8x64) @ H^T(64x64).
    // k-map for all A/B packs: (q,e) -> k = 4q+e (e<4), 16+4q+(e-4) (e>=4).
    // C/D layout (m89-verified): col=lane&15, row=4*(lane>>4)+reg.

    // ---- stage F hi plane -> read frags -> overwrite lo plane -> read ------
    short8 fbh[4], fbl[4];
    {
        short8* F = (short8*)wb;   // [qq*64 + lane], 16B per entry = 4KB
#pragma unroll
        for (int qq = 0; qq < 4; ++qq) {
            short8 vh;
#pragma unroll
            for (int e = 0; e < 8; ++e) {
                const int f = (e < 4) ? (4 * qq + e) : (16 + 4 * qq + (e - 4));
                vh[e] = bf16_hi(fr[f]);
            }
            F[qq * 64 + lane] = vh;
        }
        asm volatile("s_waitcnt lgkmcnt(0)" ::: "memory");
#pragma unroll
        for (int nt = 0; nt < 4; ++nt)
            fbh[nt] = *(const short8*)(wb + (q * 1024 + (16 * nt + cc) * 16));
        asm volatile("s_waitcnt lgkmcnt(0)" ::: "memory");  // reads done before overwrite
#pragma unroll
        for (int qq = 0; qq < 4; ++qq) {
            short8 vl;
#pragma unroll
            for (int e = 0; e < 8; ++e) {
                const int f = (e < 4) ? (4 * qq + e) : (16 + 4 * qq + (e - 4));
                float x = fr[f];
                short h = bf16_hi(x);
                vl[e] = bf16_hi(x - bf16_back(h));
            }
            F[qq * 64 + lane] = vl;
        }
        asm volatile("s_waitcnt lgkmcnt(0)" ::: "memory");
#pragma unroll
        for (int nt = 0; nt < 4; ++nt)
            fbl[nt] = *(const short8*)(wb + (q * 1024 + (16 * nt + cc) * 16));
        asm volatile("s_waitcnt lgkmcnt(0)" ::: "memory");
    }

    const f32x4 zero4 = {0.f, 0.f, 0.f, 0.f};
    f32x4 oacc[4] = {zero4, zero4, zero4, zero4};

#pragma unroll
    for (int kk = 0; kk < 2; ++kk) {
        // ---- layer 1, m-tiles {2kk, 2kk+1} -> hidden rows 32kk..32kk+31 ----
        f32x4 hacc[2][4];
#pragma unroll
        for (int ms = 0; ms < 2; ++ms)
#pragma unroll
            for (int nt = 0; nt < 4; ++nt) hacc[ms][nt] = zero4;

#pragma unroll
        for (int ms = 0; ms < 2; ++ms) {
            const int m = 2 * kk + ms;
            // A-frag of W1^T tile m: lane holds row 16m+cc, k = map(q,e)
            float wv[8];
#pragma unroll
            for (int e = 0; e < 8; ++e) {
                const int f = (e < 4) ? (4 * q + e) : (16 + 4 * q + (e - 4));
                wv[e] = w1[f * 64 + 16 * m + cc];
            }
            short8 ah, al;
#pragma unroll
            for (int e = 0; e < 8; ++e) {
                short h = bf16_hi(wv[e]);
                ah[e] = h;
                al[e] = bf16_hi(wv[e] - bf16_back(h));
            }
#pragma unroll
            for (int nt = 0; nt < 4; ++nt) {
                hacc[ms][nt] = __builtin_amdgcn_mfma_f32_16x16x32_bf16(ah, fbh[nt], hacc[ms][nt], 0, 0, 0);
                hacc[ms][nt] = __builtin_amdgcn_mfma_f32_16x16x32_bf16(ah, fbl[nt], hacc[ms][nt], 0, 0, 0);
                hacc[ms][nt] = __builtin_amdgcn_mfma_f32_16x16x32_bf16(al, fbh[nt], hacc[ms][nt], 0, 0, 0);
            }
        }

        // ---- layer 2 A-frag: W2^T, rows = out-dim (valid < 8), k = hidden --
        float wv2[8];
#pragma unroll
        for (int e = 0; e < 8; ++e) {
            const int hi_ = 32 * kk + 16 * (e >> 2) + 4 * q + (e & 3);
            const int cL = cc < 8 ? cc : 7;      // clamp addr, zero below
            float v = w2[hi_ * 8 + cL];
            wv2[e] = (cc < 8) ? v : 0.f;
        }
        short8 a2h, a2l;
#pragma unroll
        for (int e = 0; e < 8; ++e) {
            short h = bf16_hi(wv2[e]);
            a2h[e] = h;
            a2l[e] = bf16_hi(wv2[e] - bf16_back(h));
        }

        // ---- layer 2 B-frag is LANE-LOCAL: C/D col(=cc) == B-frag n(=cc),
        //      k row 4q+e / 16+4q+(e-4) == this lane's hacc[ms=e>>2][nt][e&3].
        //      Pure register repack; no LDS.
#pragma unroll
        for (int nt = 0; nt < 4; ++nt) {
            short8 bh, bl;
#pragma unroll
            for (int e = 0; e < 8; ++e) {
                float x = fmaxf(hacc[e >> 2][nt][e & 3], 0.f);
                short h = bf16_hi(x);
                bh[e] = h;
                bl[e] = bf16_hi(x - bf16_back(h));
            }
            oacc[nt] = __builtin_amdgcn_mfma_f32_16x16x32_bf16(a2h, bh, oacc[nt], 0, 0, 0);
            oacc[nt] = __builtin_amdgcn_mfma_f32_16x16x32_bf16(a2h, bl, oacc[nt], 0, 0, 0);
            oacc[nt] = __builtin_amdgcn_mfma_f32_16x16x32_bf16(a2l, bh, oacc[nt], 0, 0, 0);
        }
    }

    // ---- O^T (rows=out-j valid<8, cols=wave thread) -> per-thread rows -----
    {
        float* Ob = (float*)wb;                 // [j][t] : j*64 + t (2KB)
        if (q < 2) {
#pragma unroll
            for (int nt = 0; nt < 4; ++nt)
#pragma unroll
                for (int j = 0; j < 4; ++j)
                    Ob[(4 * q + j) * 64 + 16 * nt + cc] = oacc[nt][j];
        }
        asm volatile("s_waitcnt lgkmcnt(0)" ::: "memory");

        float o[8];
#pragma unroll
        for (int j = 0; j < 8; ++j) o[j] = Ob[j * 64 + lane];

        // ---- outer trilinear weight + 8-lane reduction ---------------------
        float wt = (ax ? uu : 1.f - uu) * (ay ? vv : 1.f - vv) * (az ? wwf : 1.f - wwf);
#pragma unroll
        for (int j = 0; j < 8; ++j) {
            float v = o[j] * wt;
            v += __shfl_xor(v, 1);
            v += __shfl_xor(v, 2);
            v += __shfl_xor(v, 4);
            o[j] = v;
        }
        float r01 = (a & 1) ? o[1] : o[0];
        float r23 = (a & 1) ? o[3] : o[2];
        float r45 = (a & 1) ? o[5] : o[4];
        float r67 = (a & 1) ? o[7] : o[6];
        float r03 = (a & 2) ? r23 : r01;
        float r47 = (a & 2) ? r67 : r45;
        float r   = (a & 4) ? r47 : r03;
        out[t] = r;
    }
}

extern "C" void kernel_launch(void* const* d_in, const int* in_sizes, int n_in,
                              void* d_out, int out_size, void* d_ws, size_t ws_size,
                              hipStream_t stream) {
    const float* xyz   = (const float*)d_in[0];
    const float* bound = (const float*)d_in[1];
    const float* table = (const float*)d_in[2];
    const float* w1    = (const float*)d_in[3];
    const float* w2    = (const float*)d_in[4];
    float* out = (float*)d_out;

    const int N = in_sizes[0] / 3;          // 262144
    const int threads = N * 8;              // one thread per (point, corner)
    const int blocks = (threads + BLK - 1) / BLK;
    grid_fused<<<blocks, BLK, 0, stream>>>(xyz, bound, table, w1, w2, out, N);
}